// Round 3
// baseline (1934.994 us; speedup 1.0000x reference)
//
#include <hip/hip_runtime.h>
#include <hip/hip_cooperative_groups.h>

namespace cg = cooperative_groups;

// ---------------- constants ----------------
#define LOG_DELTA (-5.2983174f)   // ln(0.005)

// ws layout (float offsets)
constexpr size_t OFF_C1G1  = 0;                       // [12][32][50]
constexpr size_t OFF_C1G2  = 19200;                   // [12][32][50]
constexpr size_t OFF_ACCS  = 38400;                   // [16]
constexpr size_t OFF_C0G   = 38416;                   // [12][7000][50]
constexpr size_t OFF_BETA  = OFF_C0G  + 4200000;      // [600][7000]
constexpr size_t OFF_ALPHAT= OFF_BETA + 4200000;      // [600][300]
constexpr size_t OFF_INP   = OFF_ALPHAT + 180000;     // [384][400]
constexpr size_t OFF_X0    = OFF_INP  + 153600;       // [384][1600]
constexpr size_t OFF_OUT0  = OFF_X0   + 614400;       // [384][400]
constexpr size_t OFF_X1    = OFF_OUT0 + 153600;       // [384][1600]
constexpr size_t OFF_OUT1  = OFF_X1   + 614400;       // [384][400]
constexpr size_t OFF_CST   = OFF_OUT1 + 153600;       // unused
constexpr size_t OFF_MUH   = OFF_CST  + 12800;        // [384][100] (mu|ls stacked)
constexpr size_t OFF_THETA = OFF_MUH  + 38400;        // [12][32][50]
constexpr size_t OFF_LTH   = OFF_THETA+ 19200;        // unused
constexpr size_t OFF_MUW4  = OFF_LTH  + 19200;        // [50][400]
constexpr size_t OFF_LSW4  = OFF_MUW4 + 20000;        // [50][400] (contiguous with MUW4)

// ---------------- helpers ----------------
__device__ __forceinline__ float wsum64(float x){
  #pragma unroll
  for (int o = 32; o; o >>= 1) x += __shfl_down(x, o);
  return x;
}
__device__ __forceinline__ float wmax64(float x){
  #pragma unroll
  for (int o = 32; o; o >>= 1) x = fmaxf(x, __shfl_down(x, o));
  return x;
}
// lowbias32 hash -> uniform (0,1)
__device__ __forceinline__ float u01(unsigned int x){
  x ^= x >> 16; x *= 0x7feb352dU;
  x ^= x >> 15; x *= 0x846ca68bU;
  x ^= x >> 16;
  return ((float)x + 0.5f) * (1.0f/4294967296.0f);
}

// ---------------- fused prep ----------------
__global__ void prep_misc(const float* __restrict__ muW, const float* __restrict__ lsW,
                          const float* __restrict__ qmu,
                          float* __restrict__ zbase, float* __restrict__ muW4,
                          float* __restrict__ lsW4, float* __restrict__ alphT){
  for (int i = blockIdx.x*blockDim.x + threadIdx.x; i < 258416; i += gridDim.x*blockDim.x){
    if (i < 38416) zbase[i] = 0.f;
    else if (i < 58416){ int j = i - 38416; muW4[j] = muW[(j/400)*450 + (j%400)]; }
    else if (i < 78416){ int j = i - 58416; lsW4[j] = lsW[(j/400)*450 + (j%400)]; }
    else {
      int j = i - 78416; int m = j/300, r = j%300; int t = m/50, k = m%50;
      alphT[j] = qmu[((size_t)k*12 + t)*300 + r];
    }
  }
}

// ---------------- fused bias init ----------------
__global__ void bias_all(float* __restrict__ inp, float* __restrict__ X0,
                         float* __restrict__ muH2,
                         const float* __restrict__ qb,
                         const float* __restrict__ bi0, const float* __restrict__ bh0,
                         const float* __restrict__ mb,  const float* __restrict__ lb){
  // 153600 inp | 614400 X0 | 38400 muH2
  for (int i = blockIdx.x*blockDim.x + threadIdx.x; i < 806400; i += gridDim.x*blockDim.x){
    if (i < 153600) inp[i] = qb[i % 400];
    else if (i < 768000){ int j = i - 153600; int n = j % 1600; X0[j] = bi0[n] + bh0[n]; }
    else { int j = i - 768000; int n = j % 100; muH2[j] = (n < 50) ? mb[n] : lb[n-50]; }
  }
}

// ---------------- GEMM: C (+)= A[M,K] * B[N,K]^T ----------------
__device__ __forceinline__ float4 g4(const float* __restrict__ base, int row, int nrows,
                                     int ld, int k, int kend){
  float4 v; v.x = v.y = v.z = v.w = 0.f;
  if (row < nrows){
    const float* q = base + (size_t)row*ld + k;
    if (k + 3 < kend) v = *(const float4*)q;
    else {
      if (k   < kend) v.x = q[0];
      if (k+1 < kend) v.y = q[1];
      if (k+2 < kend) v.z = q[2];
      if (k+3 < kend) v.w = q[3];
    }
  }
  return v;
}

__global__ __launch_bounds__(256) void gemm_f32(
    const float* __restrict__ A, int lda,
    const float* __restrict__ B, int ldb,
    float* __restrict__ C, int ldc,
    int M, int N, int K, int kchunk,
    const float* __restrict__ bias, int direct)
{
  __shared__ __align__(16) float As[16][68];
  __shared__ __align__(16) float Bs[16][68];
  const int tid = threadIdx.x;
  const int m0 = blockIdx.y * 64, n0 = blockIdx.x * 64;
  const int kbeg = blockIdx.z * kchunk;
  const int kend = min(K, kbeg + kchunk);
  const int lm  = tid >> 2;
  const int lkq = (tid & 3) << 2;
  const int ty = tid >> 4, tx = tid & 15;
  float acc[4][4];
  #pragma unroll
  for (int i=0;i<4;++i)
    #pragma unroll
    for (int j=0;j<4;++j) acc[i][j] = 0.f;

  for (int k0 = kbeg; k0 < kend; k0 += 16){
    float4 av = g4(A, m0+lm, M, lda, k0+lkq, kend);
    float4 bv = g4(B, n0+lm, N, ldb, k0+lkq, kend);
    As[lkq+0][lm]=av.x; As[lkq+1][lm]=av.y; As[lkq+2][lm]=av.z; As[lkq+3][lm]=av.w;
    Bs[lkq+0][lm]=bv.x; Bs[lkq+1][lm]=bv.y; Bs[lkq+2][lm]=bv.z; Bs[lkq+3][lm]=bv.w;
    __syncthreads();
    #pragma unroll
    for (int kk = 0; kk < 16; ++kk){
      const float4 a = *(const float4*)&As[kk][ty<<2];
      const float4 b = *(const float4*)&Bs[kk][tx<<2];
      float ar[4] = {a.x,a.y,a.z,a.w};
      float br[4] = {b.x,b.y,b.z,b.w};
      #pragma unroll
      for (int i=0;i<4;++i)
        #pragma unroll
        for (int j=0;j<4;++j) acc[i][j] = fmaf(ar[i], br[j], acc[i][j]);
    }
    __syncthreads();
  }
  const int om = m0 + (ty<<2), on = n0 + (tx<<2);
  if (direct){
    #pragma unroll
    for (int i=0;i<4;++i)
      #pragma unroll
      for (int j=0;j<4;++j)
        if (om+i < M && on+j < N)
          C[(size_t)(om+i)*ldc + (on+j)] = acc[i][j] + (bias ? bias[on+j] : 0.f);
  } else {
    #pragma unroll
    for (int i=0;i<4;++i)
      #pragma unroll
      for (int j=0;j<4;++j)
        if (om+i < M && on+j < N)
          atomicAdd(&C[(size_t)(om+i)*ldc + (on+j)], acc[i][j]);
  }
}

// ---------------- fused persistent LSTM (cooperative) ----------------
// grid 200 x 256. Block owns u-tile of 2 (U0 = bid*2) for both layers.
// Phase A: layer0 12 steps; Phase B: X1 = out0 @ wih1^T + bih1 + bhh1 (tiled GEMM);
// Phase C: layer1 12 steps. Weights (16 whh rows x 2 layers) resident in LDS.
__global__ __launch_bounds__(256) void lstm_fused(
    const float* __restrict__ X0,   const float* __restrict__ whh0,
    const float* __restrict__ whh1, const float* __restrict__ wih1,
    const float* __restrict__ bih1, const float* __restrict__ bhh1,
    float* __restrict__ hs0, float* __restrict__ X1, float* __restrict__ hs1)
{
  cg::grid_group grid = cg::this_grid();
  __shared__ float whhs[16][400];          // rows 0..7 layer0, 8..15 layer1
  __shared__ __align__(16) float h_s[32][404];
  __shared__ float red[4][32][9];
  __shared__ __align__(16) float As[16][68];
  __shared__ __align__(16) float Bs[16][68];
  const int tid = threadIdx.x;
  const int bid = blockIdx.x;
  const int U0 = bid * 2;

  for (int lin = tid; lin < 3200; lin += 256){
    int jrow = lin / 400, r = lin % 400;
    int g = jrow >> 1, ul = jrow & 1;
    whhs[jrow][r]     = whh0[((size_t)(g*400 + U0 + ul))*400 + r];
    whhs[8 + jrow][r] = whh1[((size_t)(g*400 + U0 + ul))*400 + r];
  }
  float c0 = 0.f, c1 = 0.f;
  const int wv = tid >> 6, lane = tid & 63;
  const int bg = lane & 15, jg = lane >> 4;   // bg: b rows bg, bg+16; jg: w rows jg, jg+4
  const int rb = wv * 100;

  // ---------- phase A: layer 0 ----------
  for (int t = 0; t < 12; ++t){
    for (int lin = tid; lin < 12800; lin += 256){
      int b = lin / 400, r = lin % 400;
      h_s[b][r] = (t == 0) ? 0.f : hs0[((size_t)b*12 + (t-1))*400 + r];
    }
    __syncthreads();
    float a00=0.f,a01=0.f,a10=0.f,a11=0.f;
    #pragma unroll 4
    for (int r = rb; r < rb + 100; ++r){
      float h0v = h_s[bg][r], h1v = h_s[bg+16][r];
      float w0 = whhs[jg][r], w1 = whhs[jg+4][r];
      a00 = fmaf(h0v,w0,a00); a01 = fmaf(h0v,w1,a01);
      a10 = fmaf(h1v,w0,a10); a11 = fmaf(h1v,w1,a11);
    }
    red[wv][bg   ][jg  ] = a00; red[wv][bg   ][jg+4] = a01;
    red[wv][bg+16][jg  ] = a10; red[wv][bg+16][jg+4] = a11;
    __syncthreads();
    if (tid < 64){
      const int b = tid >> 1, ul = tid & 1;
      float gs[4];
      #pragma unroll
      for (int g = 0; g < 4; ++g){
        float s = X0[((size_t)b*12 + t)*1600 + g*400 + U0 + ul];
        #pragma unroll
        for (int w = 0; w < 4; ++w) s += red[w][b][g*2 + ul];
        gs[g] = s;
      }
      float ii = 1.f/(1.f + expf(-gs[0]));
      float ff = 1.f/(1.f + expf(-gs[1]));
      float gg = tanhf(gs[2]);
      float oo = 1.f/(1.f + expf(-gs[3]));
      c0 = ff*c0 + ii*gg;
      hs0[((size_t)b*12 + t)*400 + U0 + ul] = oo * tanhf(c0);
    }
    __threadfence();
    grid.sync();
  }

  // ---------- phase B: X1 = hs0 @ wih1^T + bih1 + bhh1 ----------
  for (int tt = bid; tt < 150; tt += 200){
    const int m0 = (tt / 25) * 64, n0 = (tt % 25) * 64;
    const int lm  = tid >> 2, lkq = (tid & 3) << 2;
    const int ty = tid >> 4, tx = tid & 15;
    float acc[4][4];
    #pragma unroll
    for (int i=0;i<4;++i)
      #pragma unroll
      for (int j=0;j<4;++j) acc[i][j] = 0.f;
    for (int k0 = 0; k0 < 400; k0 += 16){
      float4 av = g4(hs0, m0+lm, 384, 400, k0+lkq, 400);
      float4 bv = g4(wih1, n0+lm, 1600, 400, k0+lkq, 400);
      As[lkq+0][lm]=av.x; As[lkq+1][lm]=av.y; As[lkq+2][lm]=av.z; As[lkq+3][lm]=av.w;
      Bs[lkq+0][lm]=bv.x; Bs[lkq+1][lm]=bv.y; Bs[lkq+2][lm]=bv.z; Bs[lkq+3][lm]=bv.w;
      __syncthreads();
      #pragma unroll
      for (int kk = 0; kk < 16; ++kk){
        const float4 a = *(const float4*)&As[kk][ty<<2];
        const float4 b = *(const float4*)&Bs[kk][tx<<2];
        float ar[4] = {a.x,a.y,a.z,a.w};
        float br[4] = {b.x,b.y,b.z,b.w};
        #pragma unroll
        for (int i=0;i<4;++i)
          #pragma unroll
          for (int j=0;j<4;++j) acc[i][j] = fmaf(ar[i], br[j], acc[i][j]);
      }
      __syncthreads();
    }
    const int om = m0 + (ty<<2), on = n0 + (tx<<2);
    #pragma unroll
    for (int i=0;i<4;++i)
      #pragma unroll
      for (int j=0;j<4;++j)
        X1[(size_t)(om+i)*1600 + (on+j)] = acc[i][j] + bih1[on+j] + bhh1[on+j];
  }
  __threadfence();
  grid.sync();

  // ---------- phase C: layer 1 ----------
  for (int t = 0; t < 12; ++t){
    for (int lin = tid; lin < 12800; lin += 256){
      int b = lin / 400, r = lin % 400;
      h_s[b][r] = (t == 0) ? 0.f : hs1[((size_t)b*12 + (t-1))*400 + r];
    }
    __syncthreads();
    float a00=0.f,a01=0.f,a10=0.f,a11=0.f;
    #pragma unroll 4
    for (int r = rb; r < rb + 100; ++r){
      float h0v = h_s[bg][r], h1v = h_s[bg+16][r];
      float w0 = whhs[8+jg][r], w1 = whhs[8+jg+4][r];
      a00 = fmaf(h0v,w0,a00); a01 = fmaf(h0v,w1,a01);
      a10 = fmaf(h1v,w0,a10); a11 = fmaf(h1v,w1,a11);
    }
    red[wv][bg   ][jg  ] = a00; red[wv][bg   ][jg+4] = a01;
    red[wv][bg+16][jg  ] = a10; red[wv][bg+16][jg+4] = a11;
    __syncthreads();
    if (tid < 64){
      const int b = tid >> 1, ul = tid & 1;
      float gs[4];
      #pragma unroll
      for (int g = 0; g < 4; ++g){
        float s = X1[((size_t)b*12 + t)*1600 + g*400 + U0 + ul];
        #pragma unroll
        for (int w = 0; w < 4; ++w) s += red[w][b][g*2 + ul];
        gs[g] = s;
      }
      float ii = 1.f/(1.f + expf(-gs[0]));
      float ff = 1.f/(1.f + expf(-gs[1]));
      float gg = tanhf(gs[2]);
      float oo = 1.f/(1.f + expf(-gs[3]));
      c1 = ff*c1 + ii*gg;
      hs1[((size_t)b*12 + t)*400 + U0 + ul] = oo * tanhf(c1);
    }
    __threadfence();
    grid.sync();
  }
}

// ---------------- theta head (4 blocks, 8 b's each) ----------------
__global__ __launch_bounds__(512) void theta_par(
    const float* __restrict__ muH2,   // [384][100] row b*12+t, cols 0..49 mu, 50..99 ls
    const float* __restrict__ muW, const float* __restrict__ lsW,  // [50][450]
    float* __restrict__ theta,        // [12][32][50]
    float* __restrict__ accs)
{
  __shared__ float zsall[12][8][50];
  __shared__ float wm[50][51], wl[50][51];
  __shared__ float ktot;
  const int tid = threadIdx.x;
  const int b0 = blockIdx.x * 8;
  for (int i = tid; i < 2500; i += 512){
    int k = i / 50, j = i % 50;
    wm[k][j] = muW[k*450 + 400 + j];
    wl[k][j] = lsW[k*450 + 400 + j];
  }
  if (tid == 0) ktot = 0.f;
  __syncthreads();
  const float dd = expf(LOG_DELTA) + 1e-6f;
  for (int t = 0; t < 12; ++t){
    float kpart = 0.f;
    if (tid < 400){
      int bl = tid / 50, k = tid % 50, b = b0 + bl;
      float m = muH2[((size_t)b*12 + t)*100 + k];
      float l = muH2[((size_t)b*12 + t)*100 + 50 + k];
      float zp = 0.f;
      if (t > 0){
        zp = zsall[t-1][bl][k];
        float sm = 0.f, sl = 0.f;
        #pragma unroll 5
        for (int j = 0; j < 50; ++j){
          float z = zsall[t-1][bl][j];
          sm = fmaf(z, wm[k][j], sm);
          sl = fmaf(z, wl[k][j], sl);
        }
        m += sm; l += sl;
      }
      zsall[t][bl][k] = m;
      float denom = (t > 0) ? dd : (1.f + 1e-6f);
      float pls = (t > 0) ? LOG_DELTA : 0.f;
      float d = m - zp;
      kpart += (expf(l) + d*d)/denom - 1.f + pls - l;
    }
    kpart = wsum64(kpart);
    if ((tid & 63) == 0) atomicAdd(&ktot, 0.5f * kpart / 32.f);
    __syncthreads();
  }
  // theta = softmax_k(zs)
  for (int rr = tid; rr < 96; rr += 512){
    int t = rr >> 3, bl = rr & 7, b = b0 + bl;
    float m = -3.0e38f;
    for (int k = 0; k < 50; ++k) m = fmaxf(m, zsall[t][bl][k]);
    float S = 0.f;
    for (int k = 0; k < 50; ++k) S += expf(zsall[t][bl][k] - m);
    float inv = 1.f/S;
    for (int k = 0; k < 50; ++k)
      theta[((size_t)t*32 + b)*50 + k] = expf(zsall[t][bl][k] - m) * inv;
  }
  if (tid == 0) atomicAdd(&accs[6], ktot);
}

// ---------------- kld_alpha ----------------
__global__ void kld_alpha_k(const float* __restrict__ qmu, const float* __restrict__ qls,
                            float* __restrict__ accs){
  const int t = blockIdx.x / 50, k = blockIdx.x % 50;
  const size_t base  = ((size_t)k*12 + t)*300;
  const size_t pbase = ((size_t)k*12 + (t-1))*300;
  const float dd  = (t > 0) ? (expf(LOG_DELTA) + 1e-6f) : (1.f + 1e-6f);
  const float pls = (t > 0) ? LOG_DELTA : 0.f;
  float s = 0.f;
  for (int r = threadIdx.x; r < 300; r += 64){
    float qm = qmu[base + r], ql = qls[base + r];
    float pm = (t > 0) ? qmu[pbase + r] : 0.f;
    float d = qm - pm;
    s += (expf(ql) + d*d)/dd - 1.f + pls - ql;
  }
  s = wsum64(s);
  if (threadIdx.x == 0) atomicAdd(&accs[7], 0.5f * s / 50.f);
}

// ---------------- row softmax over vocab segment (in place) ----------------
__global__ __launch_bounds__(256) void softmax_seg(float* __restrict__ buf){
  const int row = blockIdx.x, part = blockIdx.y;
  float* p = buf + (size_t)row*7000 + (part ? 5000 : 0);
  const int n = part ? 2000 : 5000;
  __shared__ float sred[8];
  const int tid = threadIdx.x;
  float m = -3.0e38f;
  for (int i = tid; i < n; i += 256) m = fmaxf(m, p[i]);
  m = wmax64(m);
  if ((tid & 63) == 0) sred[tid >> 6] = m;
  __syncthreads();
  m = fmaxf(fmaxf(sred[0], sred[1]), fmaxf(sred[2], sred[3]));
  float s = 0.f;
  for (int i = tid; i < n; i += 256) s += __expf(p[i] - m);
  s = wsum64(s);
  if ((tid & 63) == 0) sred[4 + (tid >> 6)] = s;
  __syncthreads();
  s = sred[4] + sred[5] + sred[6] + sred[7];
  const float inv = 1.f/s;
  for (int i = tid; i < n; i += 256) p[i] = __expf(p[i] - m) * inv;
}

// ---------------- pass1: sample z, counts + kld_z terms ----------------
// v-tile 32, LDS 32KB -> 4 blocks/CU; launch_bounds(256,4) caps VGPR at 128 (no spill)
__global__ __launch_bounds__(256, 4) void pass1(
    const float* __restrict__ beta,   // [600][7000]
    const float* __restrict__ theta,  // [12][32][50]
    float* __restrict__ c0g,          // [12][7000][50]
    float* __restrict__ c1g1, float* __restrict__ c1g2,  // [12][32][50]
    float* __restrict__ accs)
{
  const int t = blockIdx.y;
  const int v0 = blockIdx.x * 32;
  __shared__ float th[32][50];
  __shared__ float be[50][32];
  __shared__ float c0s[32][50];
  __shared__ float c1s[2][32][50];
  __shared__ float kred[4];
  const int tid = threadIdx.x;
  for (int i = tid; i < 1600; i += 256)
    th[i/50][i%50] = theta[(size_t)t*1600 + i];
  for (int i = tid; i < 1600; i += 256){
    int k = i >> 5, vl = i & 31, v = v0 + vl;
    be[k][vl] = (v < 7000) ? beta[((size_t)t*50 + k)*7000 + v] : 0.f;
  }
  for (int i = tid; i < 1600; i += 256) ((float*)c0s)[i] = 0.f;
  for (int i = tid; i < 3200; i += 256) ((float*)c1s)[i] = 0.f;
  if (tid < 4) kred[tid] = 0.f;
  __syncthreads();

  const int b = tid >> 3, sub = tid & 7;
  float kA1 = 0.f, kB1 = 0.f, kA2 = 0.f, kB2 = 0.f;
  float a[50];
  for (int it = 0; it < 4; ++it){
    const int vl = sub + (it << 3);
    const int v = v0 + vl;
    if (v < 7000){
      float m1 = -3.0e38f;
      #pragma unroll
      for (int k = 0; k < 50; ++k){
        float s = th[b][k]*be[k][vl];
        a[k] = s; m1 = fmaxf(m1, s);
      }
      float S1 = 0.f;
      #pragma unroll
      for (int k = 0; k < 50; ++k){
        float e = __expf(a[k] - m1);
        a[k] = e; S1 += e;
      }
      const float inv = 1.f/S1;
      float F = 0.f;
      #pragma unroll
      for (int k = 0; k < 50; ++k){
        float fk = __expf(a[k]*inv);
        a[k] = fk; F += fk;
      }
      const unsigned int seed = (unsigned int)(((t*32) + b)*7000 + v);
      const float rthr = u01(seed) * F;
      float csum = 0.f; int ks = 49; bool found = false;
      #pragma unroll
      for (int k = 0; k < 50; ++k){
        csum += a[k];
        if (!found && csum >= rthr){ ks = k; found = true; }
      }
      const float pis = __expf(th[b][ks]*be[ks][vl] - m1) * inv;
      const float lpis = __logf(pis);
      const float lt = __logf(th[b][ks]);
      if (v >= 5000){ kA2 += lt; kB2 += pis*lpis; }
      else          { kA1 += lt; kB1 += pis*lpis; }
      atomicAdd(&c0s[vl][ks], 1.f);
      atomicAdd(&c1s[(v >= 5000) ? 1 : 0][b][ks], 1.f);
    }
  }
  kA1 = wsum64(kA1); kB1 = wsum64(kB1); kA2 = wsum64(kA2); kB2 = wsum64(kB2);
  if ((tid & 63) == 0){
    atomicAdd(&kred[0], kA1); atomicAdd(&kred[1], kB1);
    atomicAdd(&kred[2], kA2); atomicAdd(&kred[3], kB2);
  }
  __syncthreads();
  for (int i = tid; i < 1600; i += 256){
    int vl = i / 50, k = i % 50, v = v0 + vl;
    if (v < 7000) c0g[((size_t)t*7000 + v)*50 + k] = c0s[vl][k];
  }
  for (int i = tid; i < 1600; i += 256){
    float x1 = ((float*)c1s)[i];
    float x2 = ((float*)c1s)[1600 + i];
    if (x1 != 0.f) atomicAdd(&c1g1[(size_t)t*1600 + i], x1);
    if (x2 != 0.f) atomicAdd(&c1g2[(size_t)t*1600 + i], x2);
  }
  if (tid < 4) atomicAdd(&accs[tid], kred[tid]);
}

// ---------------- pass2: log-likelihood ----------------
__global__ __launch_bounds__(256, 4) void pass2(
    const float* __restrict__ beta, const float* __restrict__ theta,
    const float* __restrict__ c0g,
    const float* __restrict__ c1g1, const float* __restrict__ c1g2,
    const float* __restrict__ bows, float* __restrict__ accs)
{
  const int t = blockIdx.y, v0 = blockIdx.x * 32;
  __shared__ float be[50][32];
  __shared__ __align__(16) float tz[2][32][52];
  __shared__ __align__(16) float bz[32][52];
  __shared__ float sr[2];
  const int tid = threadIdx.x;
  if (tid < 2) sr[tid] = 0.f;
  for (int i = tid; i < 1600; i += 256){
    int k = i >> 5, vl = i & 31, v = v0 + vl;
    be[k][vl] = (v < 7000) ? beta[((size_t)t*50 + k)*7000 + v] : 0.f;
  }
  for (int i = tid; i < 1600; i += 256){
    int b = i / 50, k = i % 50;
    float th_ = theta[(size_t)t*1600 + i];
    tz[0][b][k] = th_ * c1g1[(size_t)t*1600 + i] * (1.f/5000.f);
    tz[1][b][k] = th_ * c1g2[(size_t)t*1600 + i] * (1.f/2000.f);
  }
  for (int i = tid; i < 128; i += 256){
    int b = i >> 2, rem = i & 3, p = rem >> 1, j = 50 + (rem & 1);
    tz[p][b][j] = 0.f;
  }
  __syncthreads();
  for (int i = tid; i < 1600; i += 256){
    int vl = i / 50, k = i % 50, v = v0 + vl;
    bz[vl][k] = (v < 7000) ? be[k][vl] * c0g[((size_t)t*7000 + v)*50 + k] * (1.f/32.f) : 0.f;
  }
  for (int i = tid; i < 64; i += 256){ int vl = i >> 1; bz[vl][50 + (i & 1)] = 0.f; }
  __syncthreads();

  const int b = tid >> 3, sub = tid & 7;
  float s1 = 0.f, s2 = 0.f;
  for (int it = 0; it < 4; ++it){
    const int vl = sub + (it << 3);
    const int v = v0 + vl;
    if (v < 7000){
      const int p = (v >= 5000);
      float dot = 0.f;
      #pragma unroll
      for (int kq = 0; kq < 13; ++kq){
        const float4 a = *(const float4*)&tz[p][b][kq << 2];
        const float4 c = *(const float4*)&bz[vl][kq << 2];
        dot += a.x*c.x + a.y*c.y + a.z*c.z + a.w*c.w;
      }
      const float w = bows[((size_t)b*12 + t)*7000 + v];
      const float l = __logf(dot) * w;
      if (p) s2 += l; else s1 += l;
    }
  }
  s1 = wsum64(s1); s2 = wsum64(s2);
  if ((tid & 63) == 0){ atomicAdd(&sr[0], s1); atomicAdd(&sr[1], s2); }
  __syncthreads();
  if (tid < 2) atomicAdd(&accs[4 + tid], sr[tid]);
}

// ---------------- finalize ----------------
__global__ void finalize_k(const float* __restrict__ accs, float* __restrict__ out){
  if (threadIdx.x == 0 && blockIdx.x == 0){
    out[0] = -(accs[4] + accs[5]) * (1.f/32.f);           // recon_loss
    out[1] = accs[6];                                     // kld_theta
    out[2] = -accs[0]/(32.f*5000.f) - accs[1]/32.f;       // kld_z1
    out[3] = -accs[2]/(32.f*2000.f) - accs[3]/32.f;       // kld_z2
    out[4] = accs[7];                                     // kld_alpha
  }
}

// ---------------- host launcher ----------------
extern "C" void kernel_launch(void* const* d_in, const int* in_sizes, int n_in,
                              void* d_out, int out_size, void* d_ws, size_t ws_size,
                              hipStream_t stream)
{
  const float* bows   = (const float*)d_in[0];
  const float* nbows  = (const float*)d_in[1];
  const float* qmap_w = (const float*)d_in[2];
  const float* qmap_b = (const float*)d_in[3];
  const float* wih0   = (const float*)d_in[4];
  const float* whh0   = (const float*)d_in[5];
  const float* bih0   = (const float*)d_in[6];
  const float* bhh0   = (const float*)d_in[7];
  const float* wih1   = (const float*)d_in[8];
  const float* whh1   = (const float*)d_in[9];
  const float* bih1   = (const float*)d_in[10];
  const float* bhh1   = (const float*)d_in[11];
  const float* muW    = (const float*)d_in[12];
  const float* muB    = (const float*)d_in[13];
  const float* lsW    = (const float*)d_in[14];
  const float* lsB    = (const float*)d_in[15];
  const float* qmu    = (const float*)d_in[16];
  const float* qlsa   = (const float*)d_in[17];
  const float* rho1w  = (const float*)d_in[18];
  const float* rho1b  = (const float*)d_in[19];
  const float* rho2w  = (const float*)d_in[20];
  const float* rho2b  = (const float*)d_in[21];

  float* ws  = (float*)d_ws;
  float* out = (float*)d_out;

  float* c1g1  = ws + OFF_C1G1;
  float* c1g2  = ws + OFF_C1G2;
  float* accs  = ws + OFF_ACCS;
  float* c0g   = ws + OFF_C0G;
  float* beta  = ws + OFF_BETA;
  float* alphT = ws + OFF_ALPHAT;
  float* inp   = ws + OFF_INP;
  float* X0    = ws + OFF_X0;
  float* out0  = ws + OFF_OUT0;
  float* X1    = ws + OFF_X1;
  float* out1  = ws + OFF_OUT1;
  float* muH2  = ws + OFF_MUH;
  float* theta = ws + OFF_THETA;
  float* muW4  = ws + OFF_MUW4;

  prep_misc<<<256, 256, 0, stream>>>(muW, lsW, qmu, c1g1, muW4, ws + OFF_LSW4, alphT);
  kld_alpha_k<<<600, 64, 0, stream>>>(qmu, qlsa, accs);
  bias_all<<<1024, 256, 0, stream>>>(inp, X0, muH2, qmap_b, bih0, bhh0, muB, lsB);

  // inp = nbows @ qmap_w^T + qmap_b   [384,400], K=7000, 12-way split-K
  gemm_f32<<<dim3(7,6,12), 256, 0, stream>>>(nbows, 7000, qmap_w, 7000, inp, 400,
                                             384, 400, 7000, 592, nullptr, 0);
  // X0 = inp @ wih0^T + bih0 + bhh0
  gemm_f32<<<dim3(25,6,2), 256, 0, stream>>>(inp, 400, wih0, 400, X0, 1600,
                                             384, 1600, 400, 208, nullptr, 0);
  // fused LSTM: layer0 (12 steps) -> X1 GEMM -> layer1 (12 steps)
  {
    const float* a0 = X0;  const float* a1 = whh0; const float* a2 = whh1;
    const float* a3 = wih1; const float* a4 = bih1; const float* a5 = bhh1;
    float* a6 = out0; float* a7 = X1; float* a8 = out1;
    void* args[] = { (void*)&a0, (void*)&a1, (void*)&a2, (void*)&a3, (void*)&a4,
                     (void*)&a5, (void*)&a6, (void*)&a7, (void*)&a8 };
    hipLaunchCooperativeKernel((void*)lstm_fused, dim3(200), dim3(256), args, 0, stream);
  }
  // muH2 = out1 @ [muW4;lsW4]^T + bias (stacked N=100)
  gemm_f32<<<dim3(2,6,2), 256, 0, stream>>>(out1, 400, muW4, 400, muH2, 100,
                                            384, 100, 400, 208, nullptr, 0);
  theta_par<<<4, 512, 0, stream>>>(muH2, muW, lsW, theta, accs);

  // beta logits (direct store + bias), then row-softmax per segment
  gemm_f32<<<dim3(79,10,1), 256, 0, stream>>>(alphT, 300, rho1w, 300, beta, 7000,
                                              600, 5000, 300, 300, rho1b, 1);
  gemm_f32<<<dim3(32,10,1), 256, 0, stream>>>(alphT, 300, rho2w, 300, beta + 5000, 7000,
                                              600, 2000, 300, 300, rho2b, 1);
  softmax_seg<<<dim3(600,2), 256, 0, stream>>>(beta);

  // likelihood
  pass1<<<dim3(219,12), 256, 0, stream>>>(beta, theta, c0g, c1g1, c1g2, accs);
  pass2<<<dim3(219,12), 256, 0, stream>>>(beta, theta, c0g, c1g1, c1g2, bows, accs);

  finalize_k<<<1, 64, 0, stream>>>(accs, out);
}

// Round 4
// 847.478 us; speedup vs baseline: 2.2832x; 2.2832x over previous
//
#include <hip/hip_runtime.h>

// ---------------- constants ----------------
#define LOG_DELTA (-5.2983174f)   // ln(0.005)

// ws layout (float offsets)
constexpr size_t OFF_C1G1  = 0;                       // [12][32][50]
constexpr size_t OFF_C1G2  = 19200;                   // [12][32][50]
constexpr size_t OFF_ACCS  = 38400;                   // [16]
constexpr size_t OFF_C0G   = 38416;                   // [12][7000][50]
constexpr size_t OFF_BETA  = OFF_C0G  + 4200000;      // [600][7000]
constexpr size_t OFF_ALPHAT= OFF_BETA + 4200000;      // [600][300]
constexpr size_t OFF_INP   = OFF_ALPHAT + 180000;     // [384][400]
constexpr size_t OFF_X0    = OFF_INP  + 153600;       // [384][1600]
constexpr size_t OFF_OUT0  = OFF_X0   + 614400;       // [384][400]
constexpr size_t OFF_X1    = OFF_OUT0 + 153600;       // [384][1600]
constexpr size_t OFF_OUT1  = OFF_X1   + 614400;       // [384][400]
constexpr size_t OFF_CST   = OFF_OUT1 + 153600;       // [32][400]
constexpr size_t OFF_MUH   = OFF_CST  + 12800;        // [384][100] (mu|ls stacked)
constexpr size_t OFF_THETA = OFF_MUH  + 38400;        // [12][32][50]
constexpr size_t OFF_LTH   = OFF_THETA+ 19200;        // bsum0[1600]|bsum1[1600]|mlb[100]
constexpr size_t OFF_MUW4  = OFF_LTH  + 19200;        // [50][400]
constexpr size_t OFF_LSW4  = OFF_MUW4 + 20000;        // [50][400] (contiguous with MUW4)
// whh transposed-packed buffers live in the (pre-pass1 dead) c0g region:
constexpr size_t OFF_W0T   = OFF_C0G;                 // [400][1600]
constexpr size_t OFF_W1T   = OFF_C0G + 640000;        // [400][1600]

// ---------------- helpers ----------------
__device__ __forceinline__ float wsum64(float x){
  #pragma unroll
  for (int o = 32; o; o >>= 1) x += __shfl_down(x, o);
  return x;
}
__device__ __forceinline__ float wmax64(float x){
  #pragma unroll
  for (int o = 32; o; o >>= 1) x = fmaxf(x, __shfl_down(x, o));
  return x;
}
// lowbias32 hash -> uniform (0,1)
__device__ __forceinline__ float u01(unsigned int x){
  x ^= x >> 16; x *= 0x7feb352dU;
  x ^= x >> 15; x *= 0x846ca68bU;
  x ^= x >> 16;
  return ((float)x + 0.5f) * (1.0f/4294967296.0f);
}

// ---------------- fused prep ----------------
// [0,38416) zero c1g1/c1g2/accs; [38416,58416) muW4; [58416,78416) lsW4;
// [78416,258416) alphaT; [258416,260016) bsum0; [260016,261616) bsum1;
// [261616,261716) mlb; [261716,415316) inp = qb broadcast
__global__ void prep_misc(const float* __restrict__ muW, const float* __restrict__ lsW,
                          const float* __restrict__ qmu,
                          const float* __restrict__ bi0, const float* __restrict__ bh0,
                          const float* __restrict__ bi1, const float* __restrict__ bh1,
                          const float* __restrict__ mb,  const float* __restrict__ lb,
                          const float* __restrict__ qb,
                          float* __restrict__ zbase, float* __restrict__ muW4,
                          float* __restrict__ lsW4, float* __restrict__ alphT,
                          float* __restrict__ bsum0, float* __restrict__ bsum1,
                          float* __restrict__ mlb,   float* __restrict__ inp){
  for (int i = blockIdx.x*blockDim.x + threadIdx.x; i < 415316; i += gridDim.x*blockDim.x){
    if (i < 38416) zbase[i] = 0.f;
    else if (i < 58416){ int j = i - 38416; muW4[j] = muW[(j/400)*450 + (j%400)]; }
    else if (i < 78416){ int j = i - 58416; lsW4[j] = lsW[(j/400)*450 + (j%400)]; }
    else if (i < 258416){
      int j = i - 78416; int m = j/300, r = j%300; int t = m/50, k = m%50;
      alphT[j] = qmu[((size_t)k*12 + t)*300 + r];
    }
    else if (i < 260016){ int j = i - 258416; bsum0[j] = bi0[j] + bh0[j]; }
    else if (i < 261616){ int j = i - 260016; bsum1[j] = bi1[j] + bh1[j]; }
    else if (i < 261716){ int j = i - 261616; mlb[j] = (j < 50) ? mb[j] : lb[j-50]; }
    else { int j = i - 261716; inp[j] = qb[j % 400]; }
  }
}

// ---------------- whh transpose-pack: wT[r][u*4+g] = whh[g*400+u][r] ----------------
__global__ void prep_whT(const float* __restrict__ whh0, const float* __restrict__ whh1,
                         float* __restrict__ w0T, float* __restrict__ w1T){
  for (int i = blockIdx.x*blockDim.x + threadIdx.x; i < 1280000; i += gridDim.x*blockDim.x){
    int half = i / 640000, j = i % 640000;
    int r = j / 1600, col = j % 1600;
    int u = col >> 2, g = col & 3;
    float v = (half ? whh1 : whh0)[((size_t)(g*400 + u))*400 + r];
    (half ? w1T : w0T)[j] = v;
  }
}

// ---------------- GEMM: C (+)= A[M,K] * B[N,K]^T ----------------
__device__ __forceinline__ float4 g4(const float* __restrict__ base, int row, int nrows,
                                     int ld, int k, int kend){
  float4 v; v.x = v.y = v.z = v.w = 0.f;
  if (row < nrows){
    const float* q = base + (size_t)row*ld + k;
    if (k + 3 < kend) v = *(const float4*)q;
    else {
      if (k   < kend) v.x = q[0];
      if (k+1 < kend) v.y = q[1];
      if (k+2 < kend) v.z = q[2];
      if (k+3 < kend) v.w = q[3];
    }
  }
  return v;
}

__global__ __launch_bounds__(256) void gemm_f32(
    const float* __restrict__ A, int lda,
    const float* __restrict__ B, int ldb,
    float* __restrict__ C, int ldc,
    int M, int N, int K, int kchunk,
    const float* __restrict__ bias, int direct)
{
  __shared__ __align__(16) float As[16][68];
  __shared__ __align__(16) float Bs[16][68];
  const int tid = threadIdx.x;
  const int m0 = blockIdx.y * 64, n0 = blockIdx.x * 64;
  const int kbeg = blockIdx.z * kchunk;
  const int kend = min(K, kbeg + kchunk);
  const int lm  = tid >> 2;
  const int lkq = (tid & 3) << 2;
  const int ty = tid >> 4, tx = tid & 15;
  float acc[4][4];
  #pragma unroll
  for (int i=0;i<4;++i)
    #pragma unroll
    for (int j=0;j<4;++j) acc[i][j] = 0.f;

  for (int k0 = kbeg; k0 < kend; k0 += 16){
    float4 av = g4(A, m0+lm, M, lda, k0+lkq, kend);
    float4 bv = g4(B, n0+lm, N, ldb, k0+lkq, kend);
    As[lkq+0][lm]=av.x; As[lkq+1][lm]=av.y; As[lkq+2][lm]=av.z; As[lkq+3][lm]=av.w;
    Bs[lkq+0][lm]=bv.x; Bs[lkq+1][lm]=bv.y; Bs[lkq+2][lm]=bv.z; Bs[lkq+3][lm]=bv.w;
    __syncthreads();
    #pragma unroll
    for (int kk = 0; kk < 16; ++kk){
      const float4 a = *(const float4*)&As[kk][ty<<2];
      const float4 b = *(const float4*)&Bs[kk][tx<<2];
      float ar[4] = {a.x,a.y,a.z,a.w};
      float br[4] = {b.x,b.y,b.z,b.w};
      #pragma unroll
      for (int i=0;i<4;++i)
        #pragma unroll
        for (int j=0;j<4;++j) acc[i][j] = fmaf(ar[i], br[j], acc[i][j]);
    }
    __syncthreads();
  }
  const int om = m0 + (ty<<2), on = n0 + (tx<<2);
  if (direct){
    #pragma unroll
    for (int i=0;i<4;++i)
      #pragma unroll
      for (int j=0;j<4;++j)
        if (om+i < M && on+j < N)
          C[(size_t)(om+i)*ldc + (on+j)] = acc[i][j] + (bias ? bias[on+j] : 0.f);
  } else {
    #pragma unroll
    for (int i=0;i<4;++i)
      #pragma unroll
      for (int j=0;j<4;++j)
        if (om+i < M && on+j < N)
          atomicAdd(&C[(size_t)(om+i)*ldc + (on+j)], acc[i][j]);
  }
}

// ---------------- LSTM step v2 ----------------
// 50 blocks x 256 threads. Block owns u-tile of 8. Thread (b = tid>>3, u = u0+(tid&7))
// owns ALL FOUR gates of one (b,u): acc4 += h[r] * wT[r][u*4..u*4+3]. No reduction,
// no second phase; gate math in-register. h(t-1) staged once in LDS.
__global__ __launch_bounds__(256) void lstm_step2(
    const float* __restrict__ X,     // [384][1600] gates input incl. biases, row b*12+t
    const float* __restrict__ wT,    // [400][1600] packed wT[r][u*4+g]
    float* __restrict__ hs,          // [384][400] row b*12+t
    float* __restrict__ cst,         // [32][400]
    int t)
{
  __shared__ __align__(16) float h_s[32][408];
  const int tid = threadIdx.x;
  const int u0 = blockIdx.x * 8;
  const int jq = tid & 7;
  const int b  = tid >> 3;
  const int u  = u0 + jq;

  float4 acc = {0.f, 0.f, 0.f, 0.f};
  if (t > 0){
    for (int i = tid; i < 3200; i += 256){
      int bb = i / 100, rq = i % 100;
      *(float4*)&h_s[bb][rq*4] =
        *(const float4*)&hs[((size_t)(bb*12 + (t-1)))*400 + rq*4];
    }
    __syncthreads();
    const float* wcol = wT + (size_t)u*4;
    #pragma unroll 2
    for (int rq = 0; rq < 100; ++rq){
      float4 h4 = *(const float4*)&h_s[b][rq*4];
      float hr[4] = {h4.x, h4.y, h4.z, h4.w};
      #pragma unroll
      for (int dr = 0; dr < 4; ++dr){
        float4 w4 = *(const float4*)&wcol[(size_t)(rq*4 + dr)*1600];
        acc.x = fmaf(hr[dr], w4.x, acc.x);
        acc.y = fmaf(hr[dr], w4.y, acc.y);
        acc.z = fmaf(hr[dr], w4.z, acc.z);
        acc.w = fmaf(hr[dr], w4.w, acc.w);
      }
    }
  }
  const size_t xrow = ((size_t)b*12 + t)*1600;
  float gi = acc.x + X[xrow          + u];
  float gf = acc.y + X[xrow +  400   + u];
  float gg = acc.z + X[xrow +  800   + u];
  float go = acc.w + X[xrow + 1200   + u];
  float ii = 1.f/(1.f + expf(-gi));
  float ff = 1.f/(1.f + expf(-gf));
  float tg = tanhf(gg);
  float oo = 1.f/(1.f + expf(-go));
  float c = (t == 0) ? 0.f : cst[b*400 + u];
  c = ff*c + ii*tg;
  cst[b*400 + u] = c;
  hs[((size_t)b*12 + t)*400 + u] = oo * tanhf(c);
}

// ---------------- theta head (4 blocks, 8 b's each) ----------------
__global__ __launch_bounds__(512) void theta_par(
    const float* __restrict__ muH2,   // [384][100] row b*12+t, cols 0..49 mu, 50..99 ls
    const float* __restrict__ muW, const float* __restrict__ lsW,  // [50][450]
    float* __restrict__ theta,        // [12][32][50]
    float* __restrict__ accs)
{
  __shared__ float zsall[12][8][50];
  __shared__ float wm[50][51], wl[50][51];
  __shared__ float ktot;
  const int tid = threadIdx.x;
  const int b0 = blockIdx.x * 8;
  for (int i = tid; i < 2500; i += 512){
    int k = i / 50, j = i % 50;
    wm[k][j] = muW[k*450 + 400 + j];
    wl[k][j] = lsW[k*450 + 400 + j];
  }
  if (tid == 0) ktot = 0.f;
  __syncthreads();
  const float dd = expf(LOG_DELTA) + 1e-6f;
  for (int t = 0; t < 12; ++t){
    float kpart = 0.f;
    if (tid < 400){
      int bl = tid / 50, k = tid % 50, b = b0 + bl;
      float m = muH2[((size_t)b*12 + t)*100 + k];
      float l = muH2[((size_t)b*12 + t)*100 + 50 + k];
      float zp = 0.f;
      if (t > 0){
        zp = zsall[t-1][bl][k];
        float sm = 0.f, sl = 0.f;
        #pragma unroll 5
        for (int j = 0; j < 50; ++j){
          float z = zsall[t-1][bl][j];
          sm = fmaf(z, wm[k][j], sm);
          sl = fmaf(z, wl[k][j], sl);
        }
        m += sm; l += sl;
      }
      zsall[t][bl][k] = m;
      float denom = (t > 0) ? dd : (1.f + 1e-6f);
      float pls = (t > 0) ? LOG_DELTA : 0.f;
      float d = m - zp;
      kpart += (expf(l) + d*d)/denom - 1.f + pls - l;
    }
    kpart = wsum64(kpart);
    if ((tid & 63) == 0) atomicAdd(&ktot, 0.5f * kpart / 32.f);
    __syncthreads();
  }
  for (int rr = tid; rr < 96; rr += 512){
    int t = rr >> 3, bl = rr & 7, b = b0 + bl;
    float m = -3.0e38f;
    for (int k = 0; k < 50; ++k) m = fmaxf(m, zsall[t][bl][k]);
    float S = 0.f;
    for (int k = 0; k < 50; ++k) S += expf(zsall[t][bl][k] - m);
    float inv = 1.f/S;
    for (int k = 0; k < 50; ++k)
      theta[((size_t)t*32 + b)*50 + k] = expf(zsall[t][bl][k] - m) * inv;
  }
  if (tid == 0) atomicAdd(&accs[6], ktot);
}

// ---------------- kld_alpha ----------------
__global__ void kld_alpha_k(const float* __restrict__ qmu, const float* __restrict__ qls,
                            float* __restrict__ accs){
  const int t = blockIdx.x / 50, k = blockIdx.x % 50;
  const size_t base  = ((size_t)k*12 + t)*300;
  const size_t pbase = ((size_t)k*12 + (t-1))*300;
  const float dd  = (t > 0) ? (expf(LOG_DELTA) + 1e-6f) : (1.f + 1e-6f);
  const float pls = (t > 0) ? LOG_DELTA : 0.f;
  float s = 0.f;
  for (int r = threadIdx.x; r < 300; r += 64){
    float qm = qmu[base + r], ql = qls[base + r];
    float pm = (t > 0) ? qmu[pbase + r] : 0.f;
    float d = qm - pm;
    s += (expf(ql) + d*d)/dd - 1.f + pls - ql;
  }
  s = wsum64(s);
  if (threadIdx.x == 0) atomicAdd(&accs[7], 0.5f * s / 50.f);
}

// ---------------- row softmax over vocab segment (in place) ----------------
__global__ __launch_bounds__(256) void softmax_seg(float* __restrict__ buf){
  const int row = blockIdx.x, part = blockIdx.y;
  float* p = buf + (size_t)row*7000 + (part ? 5000 : 0);
  const int n = part ? 2000 : 5000;
  __shared__ float sred[8];
  const int tid = threadIdx.x;
  float m = -3.0e38f;
  for (int i = tid; i < n; i += 256) m = fmaxf(m, p[i]);
  m = wmax64(m);
  if ((tid & 63) == 0) sred[tid >> 6] = m;
  __syncthreads();
  m = fmaxf(fmaxf(sred[0], sred[1]), fmaxf(sred[2], sred[3]));
  float s = 0.f;
  for (int i = tid; i < n; i += 256) s += __expf(p[i] - m);
  s = wsum64(s);
  if ((tid & 63) == 0) sred[4 + (tid >> 6)] = s;
  __syncthreads();
  s = sred[4] + sred[5] + sred[6] + sred[7];
  const float inv = 1.f/s;
  for (int i = tid; i < n; i += 256) p[i] = __expf(p[i] - m) * inv;
}

// ---------------- pass1: sample z, counts + kld_z terms ----------------
__global__ __launch_bounds__(256, 4) void pass1(
    const float* __restrict__ beta,   // [600][7000]
    const float* __restrict__ theta,  // [12][32][50]
    float* __restrict__ c0g,          // [12][7000][50]
    float* __restrict__ c1g1, float* __restrict__ c1g2,  // [12][32][50]
    float* __restrict__ accs)
{
  const int t = blockIdx.y;
  const int v0 = blockIdx.x * 32;
  __shared__ float th[32][50];
  __shared__ float be[50][32];
  __shared__ float c0s[32][50];
  __shared__ float c1s[2][32][50];
  __shared__ float kred[4];
  const int tid = threadIdx.x;
  for (int i = tid; i < 1600; i += 256)
    th[i/50][i%50] = theta[(size_t)t*1600 + i];
  for (int i = tid; i < 1600; i += 256){
    int k = i >> 5, vl = i & 31, v = v0 + vl;
    be[k][vl] = (v < 7000) ? beta[((size_t)t*50 + k)*7000 + v] : 0.f;
  }
  for (int i = tid; i < 1600; i += 256) ((float*)c0s)[i] = 0.f;
  for (int i = tid; i < 3200; i += 256) ((float*)c1s)[i] = 0.f;
  if (tid < 4) kred[tid] = 0.f;
  __syncthreads();

  const int b = tid >> 3, sub = tid & 7;
  float kA1 = 0.f, kB1 = 0.f, kA2 = 0.f, kB2 = 0.f;
  float a[50];
  for (int it = 0; it < 4; ++it){
    const int vl = sub + (it << 3);
    const int v = v0 + vl;
    if (v < 7000){
      float m1 = -3.0e38f;
      #pragma unroll
      for (int k = 0; k < 50; ++k){
        float s = th[b][k]*be[k][vl];
        a[k] = s; m1 = fmaxf(m1, s);
      }
      float S1 = 0.f;
      #pragma unroll
      for (int k = 0; k < 50; ++k){
        float e = __expf(a[k] - m1);
        a[k] = e; S1 += e;
      }
      const float inv = 1.f/S1;
      float F = 0.f;
      #pragma unroll
      for (int k = 0; k < 50; ++k){
        float fk = __expf(a[k]*inv);
        a[k] = fk; F += fk;
      }
      const unsigned int seed = (unsigned int)(((t*32) + b)*7000 + v);
      const float rthr = u01(seed) * F;
      float csum = 0.f; int ks = 49; bool found = false;
      #pragma unroll
      for (int k = 0; k < 50; ++k){
        csum += a[k];
        if (!found && csum >= rthr){ ks = k; found = true; }
      }
      const float pis = __expf(th[b][ks]*be[ks][vl] - m1) * inv;
      const float lpis = __logf(pis);
      const float lt = __logf(th[b][ks]);
      if (v >= 5000){ kA2 += lt; kB2 += pis*lpis; }
      else          { kA1 += lt; kB1 += pis*lpis; }
      atomicAdd(&c0s[vl][ks], 1.f);
      atomicAdd(&c1s[(v >= 5000) ? 1 : 0][b][ks], 1.f);
    }
  }
  kA1 = wsum64(kA1); kB1 = wsum64(kB1); kA2 = wsum64(kA2); kB2 = wsum64(kB2);
  if ((tid & 63) == 0){
    atomicAdd(&kred[0], kA1); atomicAdd(&kred[1], kB1);
    atomicAdd(&kred[2], kA2); atomicAdd(&kred[3], kB2);
  }
  __syncthreads();
  for (int i = tid; i < 1600; i += 256){
    int vl = i / 50, k = i % 50, v = v0 + vl;
    if (v < 7000) c0g[((size_t)t*7000 + v)*50 + k] = c0s[vl][k];
  }
  for (int i = tid; i < 1600; i += 256){
    float x1 = ((float*)c1s)[i];
    float x2 = ((float*)c1s)[1600 + i];
    if (x1 != 0.f) atomicAdd(&c1g1[(size_t)t*1600 + i], x1);
    if (x2 != 0.f) atomicAdd(&c1g2[(size_t)t*1600 + i], x2);
  }
  if (tid < 4) atomicAdd(&accs[tid], kred[tid]);
}

// ---------------- pass2: log-likelihood ----------------
__global__ __launch_bounds__(256, 4) void pass2(
    const float* __restrict__ beta, const float* __restrict__ theta,
    const float* __restrict__ c0g,
    const float* __restrict__ c1g1, const float* __restrict__ c1g2,
    const float* __restrict__ bows, float* __restrict__ accs)
{
  const int t = blockIdx.y, v0 = blockIdx.x * 32;
  __shared__ float be[50][32];
  __shared__ __align__(16) float tz[2][32][52];
  __shared__ __align__(16) float bz[32][52];
  __shared__ float sr[2];
  const int tid = threadIdx.x;
  if (tid < 2) sr[tid] = 0.f;
  for (int i = tid; i < 1600; i += 256){
    int k = i >> 5, vl = i & 31, v = v0 + vl;
    be[k][vl] = (v < 7000) ? beta[((size_t)t*50 + k)*7000 + v] : 0.f;
  }
  for (int i = tid; i < 1600; i += 256){
    int b = i / 50, k = i % 50;
    float th_ = theta[(size_t)t*1600 + i];
    tz[0][b][k] = th_ * c1g1[(size_t)t*1600 + i] * (1.f/5000.f);
    tz[1][b][k] = th_ * c1g2[(size_t)t*1600 + i] * (1.f/2000.f);
  }
  for (int i = tid; i < 128; i += 256){
    int b = i >> 2, rem = i & 3, p = rem >> 1, j = 50 + (rem & 1);
    tz[p][b][j] = 0.f;
  }
  __syncthreads();
  for (int i = tid; i < 1600; i += 256){
    int vl = i / 50, k = i % 50, v = v0 + vl;
    bz[vl][k] = (v < 7000) ? be[k][vl] * c0g[((size_t)t*7000 + v)*50 + k] * (1.f/32.f) : 0.f;
  }
  for (int i = tid; i < 64; i += 256){ int vl = i >> 1; bz[vl][50 + (i & 1)] = 0.f; }
  __syncthreads();

  const int b = tid >> 3, sub = tid & 7;
  float s1 = 0.f, s2 = 0.f;
  for (int it = 0; it < 4; ++it){
    const int vl = sub + (it << 3);
    const int v = v0 + vl;
    if (v < 7000){
      const int p = (v >= 5000);
      float dot = 0.f;
      #pragma unroll
      for (int kq = 0; kq < 13; ++kq){
        const float4 a = *(const float4*)&tz[p][b][kq << 2];
        const float4 c = *(const float4*)&bz[vl][kq << 2];
        dot += a.x*c.x + a.y*c.y + a.z*c.z + a.w*c.w;
      }
      const float w = bows[((size_t)b*12 + t)*7000 + v];
      const float l = __logf(dot) * w;
      if (p) s2 += l; else s1 += l;
    }
  }
  s1 = wsum64(s1); s2 = wsum64(s2);
  if ((tid & 63) == 0){ atomicAdd(&sr[0], s1); atomicAdd(&sr[1], s2); }
  __syncthreads();
  if (tid < 2) atomicAdd(&accs[4 + tid], sr[tid]);
}

// ---------------- finalize ----------------
__global__ void finalize_k(const float* __restrict__ accs, float* __restrict__ out){
  if (threadIdx.x == 0 && blockIdx.x == 0){
    out[0] = -(accs[4] + accs[5]) * (1.f/32.f);           // recon_loss
    out[1] = accs[6];                                     // kld_theta
    out[2] = -accs[0]/(32.f*5000.f) - accs[1]/32.f;       // kld_z1
    out[3] = -accs[2]/(32.f*2000.f) - accs[3]/32.f;       // kld_z2
    out[4] = accs[7];                                     // kld_alpha
  }
}

// ---------------- host launcher ----------------
extern "C" void kernel_launch(void* const* d_in, const int* in_sizes, int n_in,
                              void* d_out, int out_size, void* d_ws, size_t ws_size,
                              hipStream_t stream)
{
  const float* bows   = (const float*)d_in[0];
  const float* nbows  = (const float*)d_in[1];
  const float* qmap_w = (const float*)d_in[2];
  const float* qmap_b = (const float*)d_in[3];
  const float* wih0   = (const float*)d_in[4];
  const float* whh0   = (const float*)d_in[5];
  const float* bih0   = (const float*)d_in[6];
  const float* bhh0   = (const float*)d_in[7];
  const float* wih1   = (const float*)d_in[8];
  const float* whh1   = (const float*)d_in[9];
  const float* bih1   = (const float*)d_in[10];
  const float* bhh1   = (const float*)d_in[11];
  const float* muW    = (const float*)d_in[12];
  const float* muB    = (const float*)d_in[13];
  const float* lsW    = (const float*)d_in[14];
  const float* lsB    = (const float*)d_in[15];
  const float* qmu    = (const float*)d_in[16];
  const float* qlsa   = (const float*)d_in[17];
  const float* rho1w  = (const float*)d_in[18];
  const float* rho1b  = (const float*)d_in[19];
  const float* rho2w  = (const float*)d_in[20];
  const float* rho2b  = (const float*)d_in[21];

  float* ws  = (float*)d_ws;
  float* out = (float*)d_out;

  float* c1g1  = ws + OFF_C1G1;
  float* c1g2  = ws + OFF_C1G2;
  float* accs  = ws + OFF_ACCS;
  float* c0g   = ws + OFF_C0G;
  float* beta  = ws + OFF_BETA;
  float* alphT = ws + OFF_ALPHAT;
  float* inp   = ws + OFF_INP;
  float* X0    = ws + OFF_X0;
  float* out0  = ws + OFF_OUT0;
  float* X1    = ws + OFF_X1;
  float* out1  = ws + OFF_OUT1;
  float* cst   = ws + OFF_CST;
  float* muH2  = ws + OFF_MUH;
  float* theta = ws + OFF_THETA;
  float* muW4  = ws + OFF_MUW4;
  float* w0T   = ws + OFF_W0T;
  float* w1T   = ws + OFF_W1T;
  float* bsum0 = ws + OFF_LTH;
  float* bsum1 = ws + OFF_LTH + 1600;
  float* mlb   = ws + OFF_LTH + 3200;

  prep_misc<<<1024, 256, 0, stream>>>(muW, lsW, qmu, bih0, bhh0, bih1, bhh1,
                                      muB, lsB, qmap_b,
                                      c1g1, muW4, ws + OFF_LSW4, alphT,
                                      bsum0, bsum1, mlb, inp);
  prep_whT<<<1280, 256, 0, stream>>>(whh0, whh1, w0T, w1T);
  kld_alpha_k<<<600, 64, 0, stream>>>(qmu, qlsa, accs);

  // inp += nbows @ qmap_w^T   [384,400], K=7000, 12-way split-K (inp pre-init by prep)
  gemm_f32<<<dim3(7,6,12), 256, 0, stream>>>(nbows, 7000, qmap_w, 7000, inp, 400,
                                             384, 400, 7000, 592, nullptr, 0);
  // X0 = inp @ wih0^T + (bih0+bhh0)  -- direct store, fused bias
  gemm_f32<<<dim3(25,6,1), 256, 0, stream>>>(inp, 400, wih0, 400, X0, 1600,
                                             384, 1600, 400, 400, bsum0, 1);
  // layer 0
  for (int t = 0; t < 12; ++t)
    lstm_step2<<<50, 256, 0, stream>>>(X0, w0T, out0, cst, t);
  // X1 = out0 @ wih1^T + (bih1+bhh1)
  gemm_f32<<<dim3(25,6,1), 256, 0, stream>>>(out0, 400, wih1, 400, X1, 1600,
                                             384, 1600, 400, 400, bsum1, 1);
  // layer 1
  for (int t = 0; t < 12; ++t)
    lstm_step2<<<50, 256, 0, stream>>>(X1, w1T, out1, cst, t);

  // muH2 = out1 @ [muW4;lsW4]^T + [muB;lsB]  (stacked N=100, direct)
  gemm_f32<<<dim3(2,6,1), 256, 0, stream>>>(out1, 400, muW4, 400, muH2, 100,
                                            384, 100, 400, 400, mlb, 1);
  theta_par<<<4, 512, 0, stream>>>(muH2, muW, lsW, theta, accs);

  // beta logits (direct store + bias), then row-softmax per segment
  gemm_f32<<<dim3(79,10,1), 256, 0, stream>>>(alphT, 300, rho1w, 300, beta, 7000,
                                              600, 5000, 300, 300, rho1b, 1);
  gemm_f32<<<dim3(32,10,1), 256, 0, stream>>>(alphT, 300, rho2w, 300, beta + 5000, 7000,
                                              600, 2000, 300, 300, rho2b, 1);
  softmax_seg<<<dim3(600,2), 256, 0, stream>>>(beta);

  // likelihood
  pass1<<<dim3(219,12), 256, 0, stream>>>(beta, theta, c0g, c1g1, c1g2, accs);
  pass2<<<dim3(219,12), 256, 0, stream>>>(beta, theta, c0g, c1g1, c1g2, bows, accs);

  finalize_k<<<1, 64, 0, stream>>>(accs, out);
}